// Round 1
// baseline (129.334 us; speedup 1.0000x reference)
//
#include <hip/hip_runtime.h>

// SupConLoss, B=8192, D=128, T=5.0
// Strategy: bf16 MFMA flash-style single pass over sim = F*F^T / T.
// Per row keep (m, Z, A, cnt) online; sim never materialized.
//   term_i = (A - cnt*m)/cnt - log(1e-12 + Z);  loss = -(1/B) * sum(term_i | cnt>0)
//
// ws layout: [0, 2MB) bf16 features; [2MB, 3MB) partials float4 [CHUNKS][B];
//            [3MB, +128B) block sums.

#define BN 8192
#define DK 128
#define INV_T 0.2f

#define CHUNKS 8
#define CHUNK_COLS (BN / CHUNKS)   // 1024
#define ROWS_PER_BLOCK 128         // 4 waves * 32 rows
#define RT_PER_WAVE 2              // two 16-row MFMA tiles per wave

typedef __attribute__((ext_vector_type(8))) short bf16x8;   // 8 bf16 = 4 VGPRs
typedef __attribute__((ext_vector_type(4))) float f32x4;

__device__ __forceinline__ unsigned short f2bf(float f) {
    // round-to-nearest-even bf16 (inputs are finite normals; no NaN path needed)
    unsigned u = __builtin_bit_cast(unsigned, f);
    u += 0x7fffu + ((u >> 16) & 1u);
    return (unsigned short)(u >> 16);
}

__global__ __launch_bounds__(256) void cast_kernel(const float* __restrict__ F,
                                                   unsigned short* __restrict__ Fb) {
    int idx = blockIdx.x * 256 + threadIdx.x;      // float4 index; grid covers BN*DK/4
    float4 v = ((const float4*)F)[idx];
    ushort4 o;
    o.x = f2bf(v.x); o.y = f2bf(v.y); o.z = f2bf(v.z); o.w = f2bf(v.w);
    ((ushort4*)Fb)[idx] = o;
}

__global__ __launch_bounds__(256) void supcon_main(const short* __restrict__ Fb,
                                                   const int* __restrict__ labels,
                                                   float4* __restrict__ part) {
    const int t    = threadIdx.x;
    const int wave = t >> 6;
    const int lane = t & 63;
    const int quad = lane >> 4;
    const int l16  = lane & 15;
    const int rowBase = blockIdx.x * ROWS_PER_BLOCK + wave * (RT_PER_WAVE * 16);
    const int colBase = blockIdx.y * CHUNK_COLS;

    // A fragments for this wave's 32 rows, all of k (verified layout:
    // elem(lane,j) = F[base + (lane&15)][kt*32 + (lane>>4)*8 + j])
    bf16x8 a[RT_PER_WAVE][4];
#pragma unroll
    for (int rt = 0; rt < RT_PER_WAVE; ++rt)
#pragma unroll
        for (int kt = 0; kt < 4; ++kt)
            a[rt][kt] = *(const bf16x8*)(Fb + (size_t)(rowBase + rt * 16 + l16) * DK
                                            + kt * 32 + quad * 8);

    // rows this lane owns in the C/D layout: row = quad*4 + r, col = lane&15
    int   rlbl[RT_PER_WAVE][4], irow[RT_PER_WAVE][4];
    float m[RT_PER_WAVE][4], Z[RT_PER_WAVE][4], A[RT_PER_WAVE][4], C[RT_PER_WAVE][4];
#pragma unroll
    for (int rt = 0; rt < RT_PER_WAVE; ++rt)
#pragma unroll
        for (int r = 0; r < 4; ++r) {
            irow[rt][r] = rowBase + rt * 16 + quad * 4 + r;
            rlbl[rt][r] = labels[irow[rt][r]];
            m[rt][r] = -__builtin_inff();
            Z[rt][r] = 0.f; A[rt][r] = 0.f; C[rt][r] = 0.f;
        }

    for (int jt = 0; jt < CHUNK_COLS / 16; ++jt) {
        const int j0 = colBase + jt * 16;
        bf16x8 b[4];
#pragma unroll
        for (int kt = 0; kt < 4; ++kt)
            b[kt] = *(const bf16x8*)(Fb + (size_t)(j0 + l16) * DK + kt * 32 + quad * 8);
        const int jcol = j0 + l16;      // this lane's column in C/D layout
        const int clbl = labels[jcol];

#pragma unroll
        for (int rt = 0; rt < RT_PER_WAVE; ++rt) {
            f32x4 acc = {0.f, 0.f, 0.f, 0.f};
#pragma unroll
            for (int kt = 0; kt < 4; ++kt)
                acc = __builtin_amdgcn_mfma_f32_16x16x32_bf16(a[rt][kt], b[kt], acc, 0, 0, 0);

#pragma unroll
            for (int r = 0; r < 4; ++r) {
                float s    = acc[r] * INV_T;
                bool  diag = (jcol == irow[rt][r]);
                float mo   = m[rt][r];
                float mn   = fmaxf(mo, s);          // max includes diagonal (ref does)
                float zs   = Z[rt][r];
                if (mn > mo) zs *= __expf(mo - mn); // rare after diag tile
                float e = __expf(s - mn);
                zs += diag ? 0.f : e;
                Z[rt][r] = zs;
                m[rt][r] = mn;
                bool match = (!diag) && (clbl == rlbl[rt][r]);
                A[rt][r] += match ? s : 0.f;
                C[rt][r] += match ? 1.f : 0.f;
            }
        }
    }

    // merge across the 16 lanes of each quad (xor of low 4 bits keeps quad)
#pragma unroll
    for (int rt = 0; rt < RT_PER_WAVE; ++rt)
#pragma unroll
        for (int r = 0; r < 4; ++r) {
            float mm = m[rt][r], zz = Z[rt][r], aa = A[rt][r], cc = C[rt][r];
#pragma unroll
            for (int h = 1; h < 16; h <<= 1) {
                float om = __shfl_xor(mm, h);
                float oz = __shfl_xor(zz, h);
                float oa = __shfl_xor(aa, h);
                float oc = __shfl_xor(cc, h);
                float mn = fmaxf(mm, om);
                zz = zz * __expf(mm - mn) + oz * __expf(om - mn);
                mm = mn; aa += oa; cc += oc;
            }
            if (l16 == 0)
                part[(size_t)blockIdx.y * BN + irow[rt][r]] = make_float4(mm, zz, aa, cc);
        }
}

__global__ __launch_bounds__(256) void supcon_finalize(const float4* __restrict__ part,
                                                       float* __restrict__ bsums) {
    const int i = blockIdx.x * 256 + threadIdx.x;
    float mm = -__builtin_inff(), zz = 0.f, aa = 0.f, cc = 0.f;
#pragma unroll
    for (int c = 0; c < CHUNKS; ++c) {
        float4 p = part[(size_t)c * BN + i];
        float mn = fmaxf(mm, p.x);
        zz = zz * __expf(mm - mn) + p.y * __expf(p.x - mn);
        mm = mn; aa += p.z; cc += p.w;
    }
    float term = 0.f;
    if (cc > 0.5f) term = (aa - cc * mm) / cc - __logf(1e-12f + zz);

    float sum = term;
#pragma unroll
    for (int h = 1; h < 64; h <<= 1) sum += __shfl_xor(sum, h);
    __shared__ float ss[4];
    if ((threadIdx.x & 63) == 0) ss[threadIdx.x >> 6] = sum;
    __syncthreads();
    if (threadIdx.x == 0) bsums[blockIdx.x] = ss[0] + ss[1] + ss[2] + ss[3];
}

__global__ void supcon_final(const float* __restrict__ bsums, float* __restrict__ out) {
    float v = (threadIdx.x < 32) ? bsums[threadIdx.x] : 0.f;
#pragma unroll
    for (int h = 1; h < 64; h <<= 1) v += __shfl_xor(v, h);
    if (threadIdx.x == 0) out[0] = -v * (1.0f / BN);
}

extern "C" void kernel_launch(void* const* d_in, const int* in_sizes, int n_in,
                              void* d_out, int out_size, void* d_ws, size_t ws_size,
                              hipStream_t stream) {
    const float* F      = (const float*)d_in[0];
    const int*   labels = (const int*)d_in[1];
    // d_in[2] (fac_label) is a no-op in the reference math.
    float* out = (float*)d_out;
    char*  ws  = (char*)d_ws;

    unsigned short* Fb   = (unsigned short*)ws;                        // 2 MB
    float4*         part = (float4*)(ws + (size_t)2 * 1024 * 1024);    // 1 MB
    float*          bsum = (float*)(ws + (size_t)3 * 1024 * 1024);     // 128 B

    cast_kernel<<<(BN * DK / 4) / 256, 256, 0, stream>>>(F, Fb);
    supcon_main<<<dim3(BN / ROWS_PER_BLOCK, CHUNKS), 256, 0, stream>>>((const short*)Fb,
                                                                       labels, part);
    supcon_finalize<<<BN / 256, 256, 0, stream>>>(part, bsum);
    supcon_final<<<1, 64, 0, stream>>>(bsum, out);
}